// Round 1
// baseline (1038.977 us; speedup 1.0000x reference)
//
#include <hip/hip_runtime.h>

// Problem constants (VectorQuantizer: B=16, D=64, H=64, W=64, K=1024)
#define DD 64
#define KK 1024
#define NPTS 65536      // B*H*W
#define TOTAL 4194304   // B*D*H*W

// Output layout (concatenated flat, all read as float32 by harness)
#define OFF_L1 4194304
#define OFF_L2 4194305
#define OFF_IDX 4194306

// ---------------- kernel 1: codebook squared norms ----------------
__global__ __launch_bounds__(256) void enorm_kernel(const float* __restrict__ e,
                                                    float* __restrict__ enorm) {
    int k = blockIdx.x * 256 + threadIdx.x;
    if (k >= KK) return;
    float s = 0.f;
#pragma unroll
    for (int d = 0; d < DD; ++d) {
        float v = e[d * KK + k];
        s = fmaf(v, v, s);
    }
    enorm[k] = s;
}

// ---------------- kernel 2: fused distance-GEMM + argmin ----------------
// Block: 256 threads. Tile: 64 points x 128 codes per iteration (8 k-tiles).
// Thread micro-tile: 4 points x 8 codes.
#define NT 64
#define KT 128

__global__ __launch_bounds__(256) void argmin_kernel(const float* __restrict__ x,
                                                     const float* __restrict__ e,
                                                     const float* __restrict__ enorm,
                                                     float* __restrict__ out_idx_f) {
    __shared__ __align__(16) float xs[DD][NT];   // 16 KB, [d][n]
    __shared__ __align__(16) float es[DD][KT];   // 32 KB, [d][k]

    const int tid = threadIdx.x;
    const int tn = tid & 15;        // 0..15 -> point group
    const int tk = tid >> 4;        // 0..15 -> code group
    const int tn4 = tn * 4;
    const int tk8 = tk * 8;

    const int n0 = blockIdx.x * NT;
    const int b  = n0 >> 12;        // n0 / 4096
    const int hw0 = n0 & 4095;

    // Load x tile: xs[d][j] = x[(b*64+d)*4096 + hw0 + j], vectorized float4.
    {
        const int j4 = (tid & 15) * 4;
        const int dbase = tid >> 4;          // 0..15
#pragma unroll
        for (int r = 0; r < 4; ++r) {
            const int d = r * 16 + dbase;
            const float4 v = *(const float4*)(x + ((b * DD + d) << 12) + hw0 + j4);
            *(float4*)(&xs[d][j4]) = v;
        }
    }

    float bv[4];
    int bi[4];
#pragma unroll
    for (int i = 0; i < 4; ++i) { bv[i] = 3.4e38f; bi[i] = 0; }

    for (int kt = 0; kt < KK / KT; ++kt) {
        const int k0 = kt * KT;
        __syncthreads();   // protect es from prior-iteration readers
        // Load e tile: es[d][kk] = e[d*K + k0 + kk], vectorized float4.
        {
            const int kk4 = (tid & 31) * 4;
            const int dbase = tid >> 5;      // 0..7
#pragma unroll
            for (int r = 0; r < 8; ++r) {
                const int d = r * 8 + dbase;
                const float4 v = *(const float4*)(e + d * KK + k0 + kk4);
                *(float4*)(&es[d][kk4]) = v;
            }
        }
        __syncthreads();

        float acc[4][8];
#pragma unroll
        for (int i = 0; i < 4; ++i)
#pragma unroll
            for (int j = 0; j < 8; ++j) acc[i][j] = 0.f;

#pragma unroll 8
        for (int d = 0; d < DD; ++d) {
            const float4 xv = *(const float4*)(&xs[d][tn4]);
            const float4 ea = *(const float4*)(&es[d][tk8]);
            const float4 eb = *(const float4*)(&es[d][tk8 + 4]);
            const float xa[4] = {xv.x, xv.y, xv.z, xv.w};
            const float ee[8] = {ea.x, ea.y, ea.z, ea.w, eb.x, eb.y, eb.z, eb.w};
#pragma unroll
            for (int i = 0; i < 4; ++i)
#pragma unroll
                for (int j = 0; j < 8; ++j)
                    acc[i][j] = fmaf(xa[i], ee[j], acc[i][j]);
        }

        // distances = ||e||^2 - 2*dot  (||x||^2 constant per point, dropped)
        float en[8];
#pragma unroll
        for (int j = 0; j < 8; ++j) en[j] = enorm[k0 + tk8 + j];
#pragma unroll
        for (int i = 0; i < 4; ++i) {
#pragma unroll
            for (int j = 0; j < 8; ++j) {
                const float dist = fmaf(-2.f, acc[i][j], en[j]);
                // strict < keeps smallest k among (near-)ties; j,kt ascend in k
                if (dist < bv[i]) { bv[i] = dist; bi[i] = k0 + tk8 + j; }
            }
        }
    }

    // Cross-thread reduction over tk (16 partials per point), reusing es LDS.
    __syncthreads();
    float* rv = &es[0][0];          // 1024 floats: [point][tk]
    float* ri = &es[0][0] + 1024;   // 1024 floats: idx stored as float (exact <=1023)
#pragma unroll
    for (int i = 0; i < 4; ++i) {
        const int p = tn4 + i;
        rv[p * 16 + tk] = bv[i];
        ri[p * 16 + tk] = (float)bi[i];
    }
    __syncthreads();
    if (tid < NT) {
        const int p = tid;
        float best = rv[p * 16];
        int bidx = (int)ri[p * 16];
#pragma unroll
        for (int t = 1; t < 16; ++t) {
            const float v = rv[p * 16 + t];
            const int id = (int)ri[p * 16 + t];
            if (v < best || (v == best && id < bidx)) { best = v; bidx = id; }
        }
        out_idx_f[n0 + p] = (float)bidx;
    }
}

// ---------------- kernel 3: gather quantized output + loss sum ----------------
__global__ __launch_bounds__(256) void quantize_kernel(const float* __restrict__ x,
                                                       const float* __restrict__ e,
                                                       const float* __restrict__ idxf,
                                                       float* __restrict__ outq,
                                                       float* __restrict__ sum) {
    const int o = blockIdx.x * 256 + threadIdx.x;   // TOTAL divisible by 256
    const int d = (o >> 12) & 63;
    const int n = ((o >> 18) << 12) | (o & 4095);   // b*4096 + h*64 + w
    const int k = (int)idxf[n];
    const float q = e[d * KK + k];
    const float xv = x[o];
    outq[o] = q;                    // straight-through forward value == q
    const float diff = xv - q;
    float v = diff * diff;
    // wave-level reduction (wave64), then one atomic per wave
#pragma unroll
    for (int off = 32; off > 0; off >>= 1) v += __shfl_down(v, off, 64);
    if ((threadIdx.x & 63) == 0) atomicAdd(sum, v);
}

// ---------------- kernel 4: finalize losses ----------------
__global__ void finalize_kernel(const float* __restrict__ sum, float* __restrict__ out) {
    const float m = sum[0] * (1.0f / (float)TOTAL);
    out[OFF_L1] = m;   // dictionary_loss
    out[OFF_L2] = m;   // commitment_loss (numerically identical)
}

extern "C" void kernel_launch(void* const* d_in, const int* in_sizes, int n_in,
                              void* d_out, int out_size, void* d_ws, size_t ws_size,
                              hipStream_t stream) {
    const float* x = (const float*)d_in[0];      // [16,64,64,64]
    const float* e = (const float*)d_in[1];      // [64,1024]
    float* out = (float*)d_out;

    float* enorm = (float*)d_ws;                 // 1024 floats
    float* sum = (float*)d_ws + 1024;            // 1 float accumulator

    hipMemsetAsync(sum, 0, sizeof(float), stream);
    enorm_kernel<<<KK / 256, 256, 0, stream>>>(e, enorm);
    argmin_kernel<<<NPTS / NT, 256, 0, stream>>>(x, e, enorm, out + OFF_IDX);
    quantize_kernel<<<TOTAL / 256, 256, 0, stream>>>(x, e, out + OFF_IDX, out, sum);
    finalize_kernel<<<1, 1, 0, stream>>>(sum, out);
}

// Round 2
// 226.522 us; speedup vs baseline: 4.5867x; 4.5867x over previous
//
#include <hip/hip_runtime.h>

// Problem constants (VectorQuantizer: B=16, D=64, H=64, W=64, K=1024)
#define DD 64
#define KK 1024
#define NPTS 65536      // B*H*W
#define TOTAL 4194304   // B*D*H*W

// Output layout (concatenated flat, all read as float32 by harness)
#define OFF_L1 4194304
#define OFF_L2 4194305
#define OFF_IDX 4194306

// ---------------- kernel 1: codebook squared norms ----------------
__global__ __launch_bounds__(256) void enorm_kernel(const float* __restrict__ e,
                                                    float* __restrict__ enorm) {
    int k = blockIdx.x * 256 + threadIdx.x;
    if (k >= KK) return;
    float s = 0.f;
#pragma unroll
    for (int d = 0; d < DD; ++d) {
        float v = e[d * KK + k];
        s = fmaf(v, v, s);
    }
    enorm[k] = s;
}

// ---------------- kernel 2: fused distance-GEMM + argmin ----------------
// Block: 256 threads. Tile: 64 points x 128 codes per iteration (8 k-tiles).
// Thread micro-tile: 4 points x 8 codes.
#define NT 64
#define KT 128

__global__ __launch_bounds__(256) void argmin_kernel(const float* __restrict__ x,
                                                     const float* __restrict__ e,
                                                     const float* __restrict__ enorm,
                                                     float* __restrict__ out_idx_f) {
    __shared__ __align__(16) float xs[DD][NT];   // 16 KB, [d][n]
    __shared__ __align__(16) float es[DD][KT];   // 32 KB, [d][k]

    const int tid = threadIdx.x;
    const int tn = tid & 15;        // 0..15 -> point group
    const int tk = tid >> 4;        // 0..15 -> code group
    const int tn4 = tn * 4;
    const int tk8 = tk * 8;

    const int n0 = blockIdx.x * NT;
    const int b  = n0 >> 12;        // n0 / 4096
    const int hw0 = n0 & 4095;

    // Load x tile: xs[d][j] = x[(b*64+d)*4096 + hw0 + j], vectorized float4.
    {
        const int j4 = (tid & 15) * 4;
        const int dbase = tid >> 4;          // 0..15
#pragma unroll
        for (int r = 0; r < 4; ++r) {
            const int d = r * 16 + dbase;
            const float4 v = *(const float4*)(x + ((b * DD + d) << 12) + hw0 + j4);
            *(float4*)(&xs[d][j4]) = v;
        }
    }

    float bv[4];
    int bi[4];
#pragma unroll
    for (int i = 0; i < 4; ++i) { bv[i] = 3.4e38f; bi[i] = 0; }

    for (int kt = 0; kt < KK / KT; ++kt) {
        const int k0 = kt * KT;
        __syncthreads();   // protect es from prior-iteration readers
        // Load e tile: es[d][kk] = e[d*K + k0 + kk], vectorized float4.
        {
            const int kk4 = (tid & 31) * 4;
            const int dbase = tid >> 5;      // 0..7
#pragma unroll
            for (int r = 0; r < 8; ++r) {
                const int d = r * 8 + dbase;
                const float4 v = *(const float4*)(e + d * KK + k0 + kk4);
                *(float4*)(&es[d][kk4]) = v;
            }
        }
        __syncthreads();

        float acc[4][8];
#pragma unroll
        for (int i = 0; i < 4; ++i)
#pragma unroll
            for (int j = 0; j < 8; ++j) acc[i][j] = 0.f;

#pragma unroll 8
        for (int d = 0; d < DD; ++d) {
            const float4 xv = *(const float4*)(&xs[d][tn4]);
            const float4 ea = *(const float4*)(&es[d][tk8]);
            const float4 eb = *(const float4*)(&es[d][tk8 + 4]);
            const float xa[4] = {xv.x, xv.y, xv.z, xv.w};
            const float ee[8] = {ea.x, ea.y, ea.z, ea.w, eb.x, eb.y, eb.z, eb.w};
#pragma unroll
            for (int i = 0; i < 4; ++i)
#pragma unroll
                for (int j = 0; j < 8; ++j)
                    acc[i][j] = fmaf(xa[i], ee[j], acc[i][j]);
        }

        // distances = ||e||^2 - 2*dot  (||x||^2 constant per point, dropped)
        float en[8];
#pragma unroll
        for (int j = 0; j < 8; ++j) en[j] = enorm[k0 + tk8 + j];
#pragma unroll
        for (int i = 0; i < 4; ++i) {
#pragma unroll
            for (int j = 0; j < 8; ++j) {
                const float dist = fmaf(-2.f, acc[i][j], en[j]);
                // strict < keeps smallest k among (near-)ties; j,kt ascend in k
                if (dist < bv[i]) { bv[i] = dist; bi[i] = k0 + tk8 + j; }
            }
        }
    }

    // Cross-thread reduction over tk (16 partials per point), reusing es LDS.
    __syncthreads();
    float* rv = &es[0][0];          // 1024 floats: [point][tk]
    float* ri = &es[0][0] + 1024;   // 1024 floats: idx stored as float (exact <=1023)
#pragma unroll
    for (int i = 0; i < 4; ++i) {
        const int p = tn4 + i;
        rv[p * 16 + tk] = bv[i];
        ri[p * 16 + tk] = (float)bi[i];
    }
    __syncthreads();
    if (tid < NT) {
        const int p = tid;
        float best = rv[p * 16];
        int bidx = (int)ri[p * 16];
#pragma unroll
        for (int t = 1; t < 16; ++t) {
            const float v = rv[p * 16 + t];
            const int id = (int)ri[p * 16 + t];
            if (v < best || (v == best && id < bidx)) { best = v; bidx = id; }
        }
        out_idx_f[n0 + p] = (float)bidx;
    }
}

// ---------------- kernel 3: gather quantized output + loss sum ----------------
// One block per (b,d) pair: stage codebook row e[d][*] (4 KB) in LDS, gather
// from LDS, per-block reduction -> ONE atomic per block (1024 total).
__global__ __launch_bounds__(256) void quantize_kernel(const float* __restrict__ x,
                                                       const float* __restrict__ e,
                                                       const float* __restrict__ idxf,
                                                       float* __restrict__ outq,
                                                       float* __restrict__ sum) {
    __shared__ __align__(16) float es[KK];   // codebook row for this d
    __shared__ float red[4];

    const int tid = threadIdx.x;
    const int b = blockIdx.x >> 6;
    const int d = blockIdx.x & 63;

    // stage e[d][0..1023] into LDS (256 threads x float4)
    *(float4*)(&es[tid * 4]) = *(const float4*)(e + d * KK + tid * 4);
    __syncthreads();

    const float* xrow = x + ((b * DD + d) << 12);     // 4096 elements
    float* orow = outq + ((b * DD + d) << 12);
    const float* irow = idxf + (b << 12);

    float acc = 0.f;
#pragma unroll
    for (int r = 0; r < 4; ++r) {
        const int j4 = (r * 256 + tid) * 4;
        const float4 xv = *(const float4*)(xrow + j4);
        const float4 kf = *(const float4*)(irow + j4);
        const float q0 = es[(int)kf.x];
        const float q1 = es[(int)kf.y];
        const float q2 = es[(int)kf.z];
        const float q3 = es[(int)kf.w];
        float4 qv;
        qv.x = q0; qv.y = q1; qv.z = q2; qv.w = q3;
        *(float4*)(orow + j4) = qv;
        const float d0 = xv.x - q0, d1 = xv.y - q1, d2 = xv.z - q2, d3 = xv.w - q3;
        acc = fmaf(d0, d0, acc);
        acc = fmaf(d1, d1, acc);
        acc = fmaf(d2, d2, acc);
        acc = fmaf(d3, d3, acc);
    }

    // wave reduce (wave64), then cross-wave via LDS, one atomic per block
#pragma unroll
    for (int off = 32; off > 0; off >>= 1) acc += __shfl_down(acc, off, 64);
    if ((tid & 63) == 0) red[tid >> 6] = acc;
    __syncthreads();
    if (tid == 0) atomicAdd(sum, red[0] + red[1] + red[2] + red[3]);
}

// ---------------- kernel 4: finalize losses ----------------
__global__ void finalize_kernel(const float* __restrict__ sum, float* __restrict__ out) {
    const float m = sum[0] * (1.0f / (float)TOTAL);
    out[OFF_L1] = m;   // dictionary_loss
    out[OFF_L2] = m;   // commitment_loss (numerically identical)
}

extern "C" void kernel_launch(void* const* d_in, const int* in_sizes, int n_in,
                              void* d_out, int out_size, void* d_ws, size_t ws_size,
                              hipStream_t stream) {
    const float* x = (const float*)d_in[0];      // [16,64,64,64]
    const float* e = (const float*)d_in[1];      // [64,1024]
    float* out = (float*)d_out;

    float* enorm = (float*)d_ws;                 // 1024 floats
    float* sum = (float*)d_ws + 1024;            // 1 float accumulator

    hipMemsetAsync(sum, 0, sizeof(float), stream);
    enorm_kernel<<<KK / 256, 256, 0, stream>>>(e, enorm);
    argmin_kernel<<<NPTS / NT, 256, 0, stream>>>(x, e, enorm, out + OFF_IDX);
    quantize_kernel<<<16 * 64, 256, 0, stream>>>(x, e, out + OFF_IDX, out, sum);
    finalize_kernel<<<1, 1, 0, stream>>>(sum, out);
}